// Round 2
// baseline (4464.314 us; speedup 1.0000x reference)
//
#include <hip/hip_runtime.h>

typedef __bf16 bf16;
typedef __bf16 bf16x2 __attribute__((ext_vector_type(2)));
typedef __bf16 bf16x4 __attribute__((ext_vector_type(4)));
typedef __bf16 bf16x8 __attribute__((ext_vector_type(8)));
typedef float f32x4 __attribute__((ext_vector_type(4)));

constexpr int Bc = 4, Tc = 512, Dc = 1024, Hc = 16, HDc = 64, Lc = 12, Vc = 50257, FFc = 4096;
constexpr int Mc = Bc * Tc;      // 2048 rows
constexpr int Vpad = 50304;      // 393 * 128

#define DEV __device__ __forceinline__

DEV void gload16(const void* g, void* l) {
    __builtin_amdgcn_global_load_lds((const __attribute__((address_space(1))) void*)g,
                                     (__attribute__((address_space(3))) void*)l, 16, 0, 0);
}

// ---------------------------------------------------------------- embeddings
__global__ void embed_kernel(const int* __restrict__ idx, const float* __restrict__ tok,
                             const float* __restrict__ pos, float* __restrict__ x) {
    const int row = blockIdx.x;            // b*T + t
    const int t = row & (Tc - 1);
    const long tb = (long)idx[row] * Dc;
    float4 a = ((const float4*)(tok + tb))[threadIdx.x];
    float4 p = ((const float4*)(pos + (long)t * Dc))[threadIdx.x];
    a.x += p.x; a.y += p.y; a.z += p.z; a.w += p.w;
    ((float4*)(x + (long)row * Dc))[threadIdx.x] = a;
}

// ---------------------------------------------------------------- layernorm (fp32 in -> bf16 out)
__global__ void ln_kernel(const float* __restrict__ x, const float* __restrict__ g,
                          const float* __restrict__ b, bf16* __restrict__ out) {
    const int row = blockIdx.x, tid = threadIdx.x;
    const float4 v = ((const float4*)(x + (long)row * Dc))[tid];
    float s = v.x + v.y + v.z + v.w;
    float q = v.x * v.x + v.y * v.y + v.z * v.z + v.w * v.w;
    __shared__ float rs[4], rq[4];
    for (int off = 32; off; off >>= 1) { s += __shfl_down(s, off); q += __shfl_down(q, off); }
    if ((tid & 63) == 0) { rs[tid >> 6] = s; rq[tid >> 6] = q; }
    __syncthreads();
    s = rs[0] + rs[1] + rs[2] + rs[3];
    q = rq[0] + rq[1] + rq[2] + rq[3];
    const float mean = s * (1.f / Dc);
    const float var = q * (1.f / Dc) - mean * mean;
    const float rstd = rsqrtf(var + 1e-5f);
    const float4 gg = ((const float4*)g)[tid];
    const float4 bb = ((const float4*)b)[tid];
    bf16x4 o;
    o.x = (bf16)((v.x - mean) * rstd * gg.x + bb.x);
    o.y = (bf16)((v.y - mean) * rstd * gg.y + bb.y);
    o.z = (bf16)((v.z - mean) * rstd * gg.z + bb.z);
    o.w = (bf16)((v.w - mean) * rstd * gg.w + bb.w);
    ((bf16x4*)(out + (long)row * Dc))[tid] = o;
}

// ---------------------------------------------------------------- transpose + fp32->bf16 (weights)
// out[c][r] = (bf16) in[r][c];  in: [R][C] f32 (+z*inZ), out: [C][R] bf16 (+z*outZ)
__global__ void transpose_cvt(const float* __restrict__ in, bf16* __restrict__ out,
                              int R, int C, long inZ, long outZ) {
    __shared__ float tile[32][33];
    const long zi = (long)blockIdx.z * inZ;
    const long zo = (long)blockIdx.z * outZ;
    const int c0 = blockIdx.x * 32, r0 = blockIdx.y * 32;
    const int tx = threadIdx.x, ty = threadIdx.y;
    for (int i = ty; i < 32; i += 8) {
        const int r = r0 + i, c = c0 + tx;
        if (r < R && c < C) tile[i][tx] = in[zi + (long)r * C + c];
    }
    __syncthreads();
    for (int i = ty; i < 32; i += 8) {
        const int c = c0 + i, r = r0 + tx;
        if (c < C && r < R) out[zo + (long)c * R + r] = (bf16)tile[tx][i];
    }
}

// ---------------------------------------------------------------- V transpose: [B,T,H,HD] -> [B,H,HD,T] (bf16)
__global__ void transpose_v(const bf16* __restrict__ v, bf16* __restrict__ vT) {
    __shared__ bf16 tile[32][33];
    const int z = blockIdx.z, b = z >> 4, hh = z & 15;
    const int t0 = blockIdx.x * 32, d0 = blockIdx.y * 32;
    const int tx = threadIdx.x, ty = threadIdx.y;
    for (int i = ty; i < 32; i += 8)
        tile[i][tx] = v[((long)(b * Tc + t0 + i) * Hc + hh) * HDc + d0 + tx];
    __syncthreads();
    for (int i = ty; i < 32; i += 8)
        vT[((long)z * HDc + d0 + i) * Tc + t0 + tx] = tile[tx][i];
}

// ---------------------------------------------------------------- causal softmax: S f32 [.,512] -> P bf16
__global__ void softmax_causal(const float* __restrict__ S, bf16* __restrict__ P) {
    const long base = (long)blockIdx.x * Tc;
    const int q = blockIdx.x & (Tc - 1);
    const int tid = threadIdx.x;
    const float2 v = ((const float2*)(S + base))[tid];
    const float NI = -1e30f;
    const int k0 = 2 * tid, k1 = 2 * tid + 1;
    float a0 = (k0 <= q) ? v.x * 0.125f : NI;
    float a1 = (k1 <= q) ? v.y * 0.125f : NI;
    float m = fmaxf(a0, a1);
    __shared__ float red[4];
    for (int off = 32; off; off >>= 1) m = fmaxf(m, __shfl_down(m, off));
    if ((tid & 63) == 0) red[tid >> 6] = m;
    __syncthreads();
    m = fmaxf(fmaxf(red[0], red[1]), fmaxf(red[2], red[3]));
    const float e0 = (k0 <= q) ? __expf(a0 - m) : 0.f;
    const float e1 = (k1 <= q) ? __expf(a1 - m) : 0.f;
    float s = e0 + e1;
    __syncthreads();
    for (int off = 32; off; off >>= 1) s += __shfl_down(s, off);
    if ((tid & 63) == 0) red[tid >> 6] = s;
    __syncthreads();
    s = red[0] + red[1] + red[2] + red[3];
    const float inv = 1.f / s;
    bf16x2 o; o.x = (bf16)(e0 * inv); o.y = (bf16)(e1 * inv);
    ((bf16x2*)(P + base))[tid] = o;
}

// ---------------------------------------------------------------- batched bf16 MFMA GEMM, B given transposed [N][K]
// EPI: 0 = bf16 out plain; 1 = f32 out plain; 2 = f32 + bias; 3 = f32 + bias + residual; 4 = bf16 + bias + relu
template <int BM, int BN, int EPI>
__global__ __launch_bounds__(256)
void gemm_bt(const bf16* __restrict__ A, const bf16* __restrict__ Bm, void* __restrict__ Cp,
             const float* __restrict__ bias, const float* __restrict__ res,
             int M, int N, int K, int lda, int ldb, int ldc, int zdiv,
             long zA1, long zA2, long zB1, long zB2, long zC1, long zC2) {
    constexpr int BK = 32;
    constexpr int WN = (BN == 128) ? 2 : 1;
    constexpr int WM = 4 / WN;
    constexpr int WTM = BM / WM, WTN = BN / WN;
    constexpr int MF = WTM / 16, NF = WTN / 16;
    constexpr int A_LOADS = BM * BK / (256 * 8);
    constexpr int B_LOADS = BN * BK / (256 * 8);

    __shared__ bf16 As[BM * BK];
    __shared__ bf16 Bs[BN * BK];

    const int z = blockIdx.z;
    const int z1 = z / zdiv, z2 = z % zdiv;
    const bf16* Ab = A + z1 * zA1 + z2 * zA2;
    const bf16* Bb = Bm + z1 * zB1 + z2 * zB2;

    const int m0 = blockIdx.y * BM;
    const int n0 = blockIdx.x * BN;
    const int tid = threadIdx.x;
    const int lane = tid & 63, wave = tid >> 6;
    const int wm = (wave / WN) * WTM;
    const int wn = (wave % WN) * WTN;
    const int lrow = lane & 15;
    const int lk = (lane >> 4) * 8;

    f32x4 acc[MF][NF];
#pragma unroll
    for (int i = 0; i < MF; ++i)
#pragma unroll
        for (int j = 0; j < NF; ++j) acc[i][j] = 0.f;

    for (int k0 = 0; k0 < K; k0 += BK) {
        __syncthreads();
#pragma unroll
        for (int i = 0; i < A_LOADS; ++i) {
            const int e = tid * 8 + i * 2048;
            gload16(Ab + (long)(m0 + (e >> 5)) * lda + k0 + (e & 31), &As[e]);
        }
#pragma unroll
        for (int i = 0; i < B_LOADS; ++i) {
            const int e = tid * 8 + i * 2048;
            gload16(Bb + (long)(n0 + (e >> 5)) * ldb + k0 + (e & 31), &Bs[e]);
        }
        asm volatile("s_waitcnt vmcnt(0)" ::: "memory");
        __syncthreads();

        bf16x8 af[MF], bfr[NF];
#pragma unroll
        for (int i = 0; i < MF; ++i)
            af[i] = *(const bf16x8*)&As[(wm + i * 16 + lrow) * BK + lk];
#pragma unroll
        for (int j = 0; j < NF; ++j)
            bfr[j] = *(const bf16x8*)&Bs[(wn + j * 16 + lrow) * BK + lk];
#pragma unroll
        for (int i = 0; i < MF; ++i)
#pragma unroll
            for (int j = 0; j < NF; ++j)
                acc[i][j] = __builtin_amdgcn_mfma_f32_16x16x32_bf16(af[i], bfr[j], acc[i][j], 0, 0, 0);
    }

    const long cz = z1 * zC1 + z2 * zC2;
    const int lcol = lane & 15;
    const int lr0 = (lane >> 4) * 4;
#pragma unroll
    for (int i = 0; i < MF; ++i) {
#pragma unroll
        for (int j = 0; j < NF; ++j) {
            const int n = n0 + wn + j * 16 + lcol;
            if (n >= N) continue;
            float bv = 0.f;
            if (EPI == 2 || EPI == 3 || EPI == 4) bv = bias[n];
#pragma unroll
            for (int r = 0; r < 4; ++r) {
                const int m = m0 + wm + i * 16 + lr0 + r;
                const long off = cz + (long)m * ldc + n;
                const float val = acc[i][j][r] + bv;
                if (EPI == 0) ((bf16*)Cp)[off] = (bf16)val;
                else if (EPI == 4) ((bf16*)Cp)[off] = (bf16)fmaxf(val, 0.f);
                else if (EPI == 3) ((float*)Cp)[off] = val + res[off];
                else ((float*)Cp)[off] = val;
            }
        }
    }
}

// ---------------------------------------------------------------- host
extern "C" void kernel_launch(void* const* d_in, const int* in_sizes, int n_in,
                              void* d_out, int out_size, void* d_ws, size_t ws_size,
                              hipStream_t stream) {
    (void)in_sizes; (void)n_in; (void)out_size; (void)ws_size;
    const int*   idx  = (const int*)d_in[0];
    const float* tok  = (const float*)d_in[1];
    const float* pos  = (const float*)d_in[2];
    const float* Wq   = (const float*)d_in[3];
    const float* Wk   = (const float*)d_in[4];
    const float* Wv   = (const float*)d_in[5];
    const float* Wo   = (const float*)d_in[6];
    const float* bo   = (const float*)d_in[7];
    const float* ln1g = (const float*)d_in[8];
    const float* ln1b = (const float*)d_in[9];
    const float* ln2g = (const float*)d_in[10];
    const float* ln2b = (const float*)d_in[11];
    const float* W1   = (const float*)d_in[12];
    const float* b1   = (const float*)d_in[13];
    const float* W2   = (const float*)d_in[14];
    const float* b2   = (const float*)d_in[15];
    const float* lnfg = (const float*)d_in[16];
    const float* lnfb = (const float*)d_in[17];
    const float* Wlm  = (const float*)d_in[18];
    const float* blm  = (const float*)d_in[19];
    float* out = (float*)d_out;

    char* w = (char*)d_ws;
    auto alloc = [&](size_t bytes) { char* p = w; w += (bytes + 255) & ~(size_t)255; return p; };
    bf16*  wqkvT = (bf16*)alloc((size_t)Lc * 3 * Dc * Dc * 2);
    bf16*  woT   = (bf16*)alloc((size_t)Lc * Dc * Dc * 2);
    bf16*  w1T   = (bf16*)alloc((size_t)Lc * Dc * FFc * 2);
    bf16*  w2T   = (bf16*)alloc((size_t)Lc * Dc * FFc * 2);
    bf16*  wlmT  = (bf16*)alloc((size_t)Vpad * Dc * 2);
    float* x     = (float*)alloc((size_t)Mc * Dc * 4);
    bf16*  h     = (bf16*)alloc((size_t)Mc * Dc * 2);
    bf16*  qkv   = (bf16*)alloc((size_t)3 * Mc * Dc * 2);
    bf16*  vT    = (bf16*)alloc((size_t)Mc * Dc * 2);
    float* S     = (float*)alloc((size_t)Bc * Hc * Tc * Tc * 4);
    bf16*  P     = (bf16*)alloc((size_t)Bc * Hc * Tc * Tc * 2);
    bf16*  attnO = (bf16*)alloc((size_t)Mc * Dc * 2);
    bf16*  f1    = (bf16*)alloc((size_t)Mc * FFc * 2);

    const dim3 tb(32, 8);
    const long DD = (long)Dc * Dc;
    const long DF = (long)Dc * FFc;

    // weight transposes (fp32 -> bf16, [K][N] -> [N][K])
    transpose_cvt<<<dim3(Dc / 32, Dc / 32, Lc), tb, 0, stream>>>(Wq, wqkvT,          Dc, Dc, DD, 3 * DD);
    transpose_cvt<<<dim3(Dc / 32, Dc / 32, Lc), tb, 0, stream>>>(Wk, wqkvT + DD,     Dc, Dc, DD, 3 * DD);
    transpose_cvt<<<dim3(Dc / 32, Dc / 32, Lc), tb, 0, stream>>>(Wv, wqkvT + 2 * DD, Dc, Dc, DD, 3 * DD);
    transpose_cvt<<<dim3(Dc / 32, Dc / 32, Lc), tb, 0, stream>>>(Wo, woT,            Dc, Dc, DD, DD);
    transpose_cvt<<<dim3(FFc / 32, Dc / 32, Lc), tb, 0, stream>>>(W1, w1T, Dc, FFc, DF, DF);
    transpose_cvt<<<dim3(Dc / 32, FFc / 32, Lc), tb, 0, stream>>>(W2, w2T, FFc, Dc, DF, DF);
    transpose_cvt<<<dim3((Vc + 31) / 32, Dc / 32, 1), tb, 0, stream>>>(Wlm, wlmT, Dc, Vc, 0, 0);

    embed_kernel<<<Mc, 256, 0, stream>>>(idx, tok, pos, x);

    for (int l = 0; l < Lc; ++l) {
        ln_kernel<<<Mc, 256, 0, stream>>>(x, ln1g + l * Dc, ln1b + l * Dc, h);
        // QKV: batch=3 over {Wq,Wk,Wv}
        gemm_bt<128, 128, 0><<<dim3(Dc / 128, Mc / 128, 3), 256, 0, stream>>>(
            h, wqkvT + (size_t)l * 3 * DD, qkv, nullptr, nullptr,
            Mc, Dc, Dc, Dc, Dc, Dc, 1,
            0, 0, DD, 0, (long)Mc * Dc, 0);
        transpose_v<<<dim3(Tc / 32, HDc / 32, Bc * Hc), tb, 0, stream>>>(qkv + 2 * (size_t)Mc * Dc, vT);
        // S = Q K^T  (batch over b,h)
        gemm_bt<128, 128, 1><<<dim3(Tc / 128, Tc / 128, Bc * Hc), 256, 0, stream>>>(
            qkv, qkv + (size_t)Mc * Dc, S, nullptr, nullptr,
            Tc, Tc, HDc, Dc, Dc, Tc, Hc,
            (long)Tc * Dc, HDc, (long)Tc * Dc, HDc, (long)Hc * Tc * Tc, (long)Tc * Tc);
        softmax_causal<<<Bc * Hc * Tc, 256, 0, stream>>>(S, P);
        // O = P V
        gemm_bt<128, 64, 0><<<dim3(1, Tc / 128, Bc * Hc), 256, 0, stream>>>(
            P, vT, attnO, nullptr, nullptr,
            Tc, HDc, Tc, Tc, Tc, Dc, Hc,
            (long)Hc * Tc * Tc, (long)Tc * Tc, (long)Hc * HDc * Tc, (long)HDc * Tc, (long)Tc * Dc, HDc);
        // x += O Wo + bo
        gemm_bt<128, 64, 3><<<dim3(Dc / 64, Mc / 128, 1), 256, 0, stream>>>(
            attnO, woT + (size_t)l * DD, x, bo + l * Dc, x,
            Mc, Dc, Dc, Dc, Dc, Dc, 1, 0, 0, 0, 0, 0, 0);
        ln_kernel<<<Mc, 256, 0, stream>>>(x, ln2g + l * Dc, ln2b + l * Dc, h);
        // f1 = relu(h W1 + b1)
        gemm_bt<128, 128, 4><<<dim3(FFc / 128, Mc / 128, 1), 256, 0, stream>>>(
            h, w1T + (size_t)l * DF, f1, b1 + l * FFc, nullptr,
            Mc, FFc, Dc, Dc, Dc, FFc, 1, 0, 0, 0, 0, 0, 0);
        // x += f1 W2 + b2
        gemm_bt<128, 64, 3><<<dim3(Dc / 64, Mc / 128, 1), 256, 0, stream>>>(
            f1, w2T + (size_t)l * DF, x, b2 + l * Dc, x,
            Mc, Dc, FFc, FFc, FFc, Dc, 1, 0, 0, 0, 0, 0, 0);
    }

    ln_kernel<<<Mc, 256, 0, stream>>>(x, lnfg, lnfb, h);
    // logits = h Wlm + blm
    gemm_bt<128, 128, 2><<<dim3(Vpad / 128, Mc / 128, 1), 256, 0, stream>>>(
        h, wlmT, out, blm, nullptr,
        Mc, Vc, Dc, Dc, Dc, Vc, 1, 0, 0, 0, 0, 0, 0);
}